// Round 2
// baseline (112.183 us; speedup 1.0000x reference)
//
#include <hip/hip_runtime.h>

// Problem constants (fixed by the reference): B=32, S=512, VDIM=256, MAX_LEN=13, 20 letters.
#define SLEN 512
#define VDIM 256
#define NBATCH 32
#define ML 13
#define NLET 20

#define BC 4              // b-chunks per s  -> grid = SLEN*BC blocks
#define NBB (NBATCH / BC) // 8 batches per block
#define XVP 272           // padded leading dim for x in LDS (272 mod 32 = 16 -> <=2-way on reads)

// ---------------------------------------------------------------------------
// Kernel 1: Wc[l][a][u] = sum_v W_out[l][a][v] * W_hid[l][v][u]
// Fusing the two VecLinears: y = (Wo @ Wh) @ x. Only 17M MACs total.
// grid (NLET, 8 u-chunks of 32), block 256 = 32 u-lanes x 8 v-splits
// -> 160 blocks (63% of chip). W_hid read exactly once (5.2 MB).
// W_out redundancy x8 (~2 MB, L2-resident).
// ---------------------------------------------------------------------------
__global__ __launch_bounds__(256) void build_wc_kernel(
    const float* __restrict__ W_hid,   // (20, V, V)
    const float* __restrict__ W_out,   // (20, ML, V)
    float* __restrict__ Wc)            // (20, ML, V)  in d_ws
{
    const int l  = blockIdx.x;
    const int uq = blockIdx.y;         // 0..7
    const int t  = threadIdx.x;
    const int up = t & 31;             // u within 32-chunk
    const int vs = t >> 5;             // v split 0..7
    const int u  = uq * 32 + up;

    const float* wh = W_hid + (size_t)l * VDIM * VDIM;
    const float* wo = W_out + (size_t)l * ML * VDIM;

    float acc[ML];
#pragma unroll
    for (int a = 0; a < ML; ++a) acc[a] = 0.f;

#pragma unroll 4
    for (int vv = 0; vv < 32; ++vv) {
        const int v = vs * 32 + vv;
        const float h = wh[v * VDIM + u];        // two 128B segments per wave
#pragma unroll
        for (int a = 0; a < ML; ++a)
            acc[a] += wo[a * VDIM + v] * h;      // wo uniform -> scalar load
    }

    __shared__ float red[8][ML][32];             // 13.3 KB; addr%32==up -> 2/bank, free
#pragma unroll
    for (int a = 0; a < ML; ++a) red[vs][a][up] = acc[a];
    __syncthreads();

    for (int idx = t; idx < ML * 32; idx += 256) {
        const int a  = idx >> 5;
        const int uu = idx & 31;
        float ssum = 0.f;
#pragma unroll
        for (int vsl = 0; vsl < 8; ++vsl) ssum += red[vsl][a][uu];
        Wc[(l * ML + a) * VDIM + uq * 32 + uu] = ssum;
    }
}

// ---------------------------------------------------------------------------
// Kernel 2: out[b][off(s)+a][c] = sum_u Wc[seq[s]][a][u] * x[b][s][u][c]
// One block per (s, chunk of 8 batches). 192 threads = 48 (a,c)-slots x 4
// u-split lanes; 39 of 48 slots active (13 a x 3 c).
// Wc[l] staged coalesced into LDS once, then register fragments (16 float4)
// reused across 8 b's. Per b: ONE global_load_dwordx4 per thread (x stream,
// read exactly once from HBM), LDS transpose (u,c)->[c][u], ds_read_b128
// inner loop (<=2-way bank alias = free), 2x shfl_xor reduce, scatter-store.
// ---------------------------------------------------------------------------
__global__ __launch_bounds__(192) void decode_kernel(
    const float* __restrict__ x,       // (B, S, V, 3)
    const float* __restrict__ Wc,      // (20, ML, V)
    const int*   __restrict__ seq,     // (S)
    const int*   __restrict__ gidx,    // (NG) sorted ascending
    float* __restrict__ out,           // (B, NG, 3)
    const int NG)
{
    const int bx = blockIdx.x;
    const int s  = bx >> 2;            // / BC
    const int bc = bx & (BC - 1);
    const int t  = threadIdx.x;
    const int o  = t >> 2;             // 0..47  (a,c) slot
    const int r  = t & 3;              // u-split lane
    const int a  = o / 3;
    const int c  = o - a * 3;
    const int l  = seq[s];             // uniform per block

    __shared__ float wl[ML * VDIM];    // 13.3 KB  Wc[l] staged
    __shared__ float xl[3 * XVP];      // x transposed to [c][u], padded

    // --- cooperative coalesced stage of Wc[l] into LDS (832 float4) ---
    {
        const float4* src = reinterpret_cast<const float4*>(Wc + (size_t)l * ML * VDIM);
        float4* dst = reinterpret_cast<float4*>(wl);
#pragma unroll
        for (int k = 0; k < 5; ++k) {
            const int idx = t + k * 192;
            if (idx < (ML * VDIM) / 4) dst[idx] = src[idx];
        }
    }

    // --- output offset + valid length via binary search on gather_idx ---
    int lo = 0, hi = NG;
    const int key = s * ML;
    while (lo < hi) { int m = (lo + hi) >> 1; if (gidx[m] < key) lo = m + 1; else hi = m; }
    const int off = lo;
    int lo2 = off, hi2 = NG;
    const int key2 = key + ML;
    while (lo2 < hi2) { int m = (lo2 + hi2) >> 1; if (gidx[m] < key2) lo2 = m + 1; else hi2 = m; }
    const int len = lo2 - off;

    __syncthreads();

    // --- this thread's Wc fragment -> registers (reused for 8 b's) ---
    const bool act = (o < 39);         // a < 13
    float4 w[16];
    if (act) {
        const float* wbase = wl + a * VDIM + r * 4;
#pragma unroll
        for (int i = 0; i < 16; ++i)
            w[i] = *reinterpret_cast<const float4*>(wbase + i * 16);
    } else {
#pragma unroll
        for (int i = 0; i < 16; ++i) w[i] = make_float4(0.f, 0.f, 0.f, 0.f);
    }

    const int b0 = bc * NBB;

    // prefetch b0's x slice: one float4 per thread, contiguous + aligned
    float4 pf = *reinterpret_cast<const float4*>(
        x + (size_t)(b0 * SLEN + s) * (VDIM * 3) + t * 4);

    for (int bi = 0; bi < NBB; ++bi) {
        const int b = b0 + bi;

        // staged regs -> LDS, transposed (u,c) -> [c][u]
        {
            const float v4[4] = {pf.x, pf.y, pf.z, pf.w};
#pragma unroll
            for (int j = 0; j < 4; ++j) {
                const int idx = t * 4 + j;
                const int uu  = idx / 3;
                const int cc  = idx - uu * 3;
                xl[cc * XVP + uu] = v4[j];
            }
        }
        __syncthreads();

        // prefetch next b while we compute this one
        if (bi + 1 < NBB)
            pf = *reinterpret_cast<const float4*>(
                x + (size_t)((b + 1) * SLEN + s) * (VDIM * 3) + t * 4);

        if (act) {
            const float* xc = xl + c * XVP + r * 4;
            float sum = 0.f;
#pragma unroll
            for (int i = 0; i < 16; ++i) {
                const float4 xv = *reinterpret_cast<const float4*>(xc + i * 16);
                sum += w[i].x * xv.x + w[i].y * xv.y + w[i].z * xv.z + w[i].w * xv.w;
            }
            // reduce the 4-lane u-split (contiguous lanes -> same wave)
            sum += __shfl_xor(sum, 1);
            sum += __shfl_xor(sum, 2);
            if (r == 0 && a < len)
                out[((size_t)b * NG + off + a) * 3 + c] = sum;
        }
        __syncthreads();
    }
}

extern "C" void kernel_launch(void* const* d_in, const int* in_sizes, int n_in,
                              void* d_out, int out_size, void* d_ws, size_t ws_size,
                              hipStream_t stream) {
    const float* x_v   = (const float*)d_in[0];   // (32,512,256,3) f32
    const float* W_hid = (const float*)d_in[1];   // (20,256,256)   f32
    const float* W_out = (const float*)d_in[2];   // (20,13,256)    f32
    const int*   seq   = (const int*)d_in[3];     // (512)          i32
    const int*   gidx  = (const int*)d_in[4];     // (3745)         i32
    float*       out   = (float*)d_out;           // (32,3745,3)    f32
    float*       Wc    = (float*)d_ws;            // 20*13*256 f32 = 266 KB scratch

    const int NG = in_sizes[4];                   // 3745

    // Kernel 1: fuse the two expert weight matrices (recomputed every call;
    // d_ws is re-poisoned before each timed launch).
    build_wc_kernel<<<dim3(NLET, 8), 256, 0, stream>>>(W_hid, W_out, Wc);

    // Kernel 2: apply fused weights + scatter to concat layout.
    decode_kernel<<<dim3(SLEN * BC), 192, 0, stream>>>(x_v, Wc, seq, gidx, out, NG);
}

// Round 3
// 106.316 us; speedup vs baseline: 1.0552x; 1.0552x over previous
//
#include <hip/hip_runtime.h>

// Problem constants (fixed by the reference): B=32, S=512, VDIM=256, MAX_LEN=13, 20 letters.
#define SLEN 512
#define VDIM 256
#define NBATCH 32
#define ML 13
#define NLET 20

#define BC 4              // b-chunks per s  -> grid = SLEN*BC blocks
#define NBB (NBATCH / BC) // 8 batches per block
#define XVP 272           // padded leading dim for x in LDS (272%32=16 -> <=2-way on reads)

// RES_LENS = {3,4,5,5,6,6,6,7,7,7,7,7,8,8,8,9,10,10,11,13} packed as nibbles.
// Baked constant: the reference hard-codes this table (gather_idx is derived
// from it + seq), so off(s) = prefix-sum of len(seq[i]) replaces any search.
#define LENS_LO 0x9888777776665543ULL   // letters 0..15
#define LENS_HI 0x000000000000DBAAULL   // letters 16..19

__device__ __forceinline__ int len_of(int L) {
    unsigned long long p = (L < 16) ? LENS_LO : LENS_HI;
    return (int)((p >> ((L & 15) * 4)) & 15ULL);
}

// ---------------------------------------------------------------------------
// Kernel 1: Wc[l][a][u] = sum_v W_out[l][a][v] * W_hid[l][v][u]   (17M MACs)
// grid (20, 16 u-chunks of 16), block 256 = 16 u-lanes x 16 v-splits
// -> 320 blocks (full chip). W_hid read exactly once (5.2 MB).
// ---------------------------------------------------------------------------
__global__ __launch_bounds__(256) void build_wc_kernel(
    const float* __restrict__ W_hid,   // (20, V, V)
    const float* __restrict__ W_out,   // (20, ML, V)
    float* __restrict__ Wc)            // (20, ML, V)  in d_ws
{
    const int l  = blockIdx.x;
    const int uq = blockIdx.y;         // 0..15
    const int t  = threadIdx.x;
    const int up = t & 15;             // u within 16-chunk
    const int vs = t >> 4;             // v split 0..15
    const int u  = uq * 16 + up;

    const float* wh = W_hid + (size_t)l * VDIM * VDIM;
    const float* wo = W_out + (size_t)l * ML * VDIM;

    float acc[ML];
#pragma unroll
    for (int a = 0; a < ML; ++a) acc[a] = 0.f;

#pragma unroll 4
    for (int vv = 0; vv < 16; ++vv) {
        const int v = vs * 16 + vv;
        const float h = wh[v * VDIM + u];        // 4 x 64B segments per wave
#pragma unroll
        for (int a = 0; a < ML; ++a)
            acc[a] += wo[a * VDIM + v] * h;      // 4 distinct addrs/wave, L2-hot
    }

    __shared__ float red[16][ML][16];            // 13.3 KB; 2-way alias = free
#pragma unroll
    for (int a = 0; a < ML; ++a) red[vs][a][up] = acc[a];
    __syncthreads();

    const int idx = t;                           // 208 outputs, one round
    if (idx < ML * 16) {
        const int a  = idx >> 4;
        const int uu = idx & 15;
        float ssum = 0.f;
#pragma unroll
        for (int vsl = 0; vsl < 16; ++vsl) ssum += red[vsl][a][uu];
        Wc[(l * ML + a) * VDIM + uq * 16 + uu] = ssum;
    }
}

// ---------------------------------------------------------------------------
// Kernel 2: out[b][off(s)+a][c] = sum_u Wc[seq[s]][a][u] * x[b][s][u][c]
// One block per (s, chunk of 8 batches). 192 threads = 48 (a,c)-slots x 4
// u-split lanes; 39 active (13 a x 3 c).
// off(s): cooperative prefix-sum over seq (no dependent-load search).
// Wc[l] staged coalesced to LDS once -> register fragments reused over 8 b's.
// Per b: ONE global_load_dwordx4 per thread (x read exactly once from HBM),
// double-buffered LDS transpose -> ONE __syncthreads per iteration,
// prefetch depth 2 keeps two b-slices in flight.
// ---------------------------------------------------------------------------
__global__ __launch_bounds__(192) void decode_kernel(
    const float* __restrict__ x,       // (B, S, V, 3)
    const float* __restrict__ Wc,      // (20, ML, V)
    const int*   __restrict__ seq,     // (S)
    float* __restrict__ out,           // (B, NG, 3)
    const int NG)
{
    const int bx = blockIdx.x;
    const int s  = bx >> 2;            // / BC
    const int bc = bx & (BC - 1);
    const int t  = threadIdx.x;
    const int o  = t >> 2;             // 0..47  (a,c) slot
    const int r  = t & 3;              // u-split lane
    const int a  = o / 3;
    const int c  = o - a * 3;
    const int wv = t >> 6;             // wave 0..2
    const int l  = seq[s];             // uniform per block

    __shared__ float wl[ML * VDIM];    // 13.3 KB  Wc[l] staged
    __shared__ float xl[2][3 * XVP];   // 6.5 KB   x transposed, double-buffered
    __shared__ int   sredi[3];

    // --- stage Wc[l] -> LDS, coalesced float4 (832 vectors) ---
    {
        const float4* src = reinterpret_cast<const float4*>(Wc + (size_t)l * ML * VDIM);
        float4* dst = reinterpret_cast<float4*>(wl);
#pragma unroll
        for (int k = 0; k < 5; ++k) {
            const int idx = t + k * 192;
            if (idx < (ML * VDIM) / 4) dst[idx] = src[idx];
        }
    }

    // --- off(s) = sum_{i<s} len(seq[i]) : <=3 coalesced loads + wave reduce ---
    int part = 0;
    for (int gi = t; gi < s; gi += 192) part += len_of(seq[gi]);
#pragma unroll
    for (int d = 1; d < 64; d <<= 1) part += __shfl_xor(part, d);
    if ((t & 63) == 0) sredi[wv] = part;

    // --- prefetch first two b-slices (depth 2) ---
    const int b0 = bc * NBB;
    const float* xs = x + (size_t)s * (VDIM * 3);
    float4 pfA = *reinterpret_cast<const float4*>(xs + (size_t)(b0    ) * SLEN * (VDIM * 3) + t * 4);
    float4 pfB = *reinterpret_cast<const float4*>(xs + (size_t)(b0 + 1) * SLEN * (VDIM * 3) + t * 4);

    __syncthreads();                   // wl + sredi ready (also drains pf loads)

    const int off = sredi[0] + sredi[1] + sredi[2];
    const int len = len_of(l);

    // --- this thread's Wc fragment -> registers (reused for 8 b's) ---
    const bool act = (o < 39);
    float4 w[16];
#pragma unroll
    for (int i = 0; i < 16; ++i) w[i] = make_float4(0.f, 0.f, 0.f, 0.f);
    if (act) {
        const float* wbase = wl + a * VDIM + r * 4;
#pragma unroll
        for (int i = 0; i < 16; ++i)
            w[i] = *reinterpret_cast<const float4*>(wbase + i * 16);
    }

    for (int bi = 0; bi < NBB; ++bi) {
        // regs -> LDS, transposed (u,c) -> [c][u], into buffer bi&1
        {
            float* xb = xl[bi & 1];
            const float v4[4] = {pfA.x, pfA.y, pfA.z, pfA.w};
#pragma unroll
            for (int j = 0; j < 4; ++j) {
                const int idx = t * 4 + j;
                const int uu  = idx / 3;
                const int cc  = idx - uu * 3;
                xb[cc * XVP + uu] = v4[j];
            }
        }
        pfA = pfB;
        if (bi + 2 < NBB)
            pfB = *reinterpret_cast<const float4*>(
                xs + (size_t)(b0 + bi + 2) * SLEN * (VDIM * 3) + t * 4);

        __syncthreads();               // single barrier per iteration

        if (act) {
            const float* xc = xl[bi & 1] + c * XVP + r * 4;
            float sum = 0.f;
#pragma unroll
            for (int i = 0; i < 16; ++i) {
                const float4 xv = *reinterpret_cast<const float4*>(xc + i * 16);
                sum += w[i].x * xv.x + w[i].y * xv.y + w[i].z * xv.z + w[i].w * xv.w;
            }
            sum += __shfl_xor(sum, 1); // fold the 4-lane u-split
            sum += __shfl_xor(sum, 2);
            if (r == 0 && a < len)
                out[((size_t)(b0 + bi) * NG + off + a) * 3 + c] = sum;
        }
    }
}

extern "C" void kernel_launch(void* const* d_in, const int* in_sizes, int n_in,
                              void* d_out, int out_size, void* d_ws, size_t ws_size,
                              hipStream_t stream) {
    const float* x_v   = (const float*)d_in[0];   // (32,512,256,3) f32
    const float* W_hid = (const float*)d_in[1];   // (20,256,256)   f32
    const float* W_out = (const float*)d_in[2];   // (20,13,256)    f32
    const int*   seq   = (const int*)d_in[3];     // (512)          i32
    float*       out   = (float*)d_out;           // (32,3745,3)    f32
    float*       Wc    = (float*)d_ws;            // 266 KB scratch

    const int NG = in_sizes[4];                   // 3745 (from gather_idx size)

    build_wc_kernel<<<dim3(NLET, 16), 256, 0, stream>>>(W_hid, W_out, Wc);
    decode_kernel<<<dim3(SLEN * BC), 192, 0, stream>>>(x_v, Wc, seq, out, NG);
}